// Round 13
// baseline (460.159 us; speedup 1.0000x reference)
//
#include <hip/hip_runtime.h>
#include <hip/hip_bf16.h>
#include <hip/hip_fp16.h>

#define N_NODES 50000
#define N_EDGES 800000
#define HIDDEN  256
#define N_GRAPHS 128

typedef _Float16 fp16x8 __attribute__((ext_vector_type(8)));
typedef float f32x4 __attribute__((ext_vector_type(4)));

// ---- fp16x4 row-chunk load + convert ----
__device__ __forceinline__ float4 h8load(const __half* p) {
    uint2 raw = *(const uint2*)p;
    __half2 h01 = *(__half2*)&raw.x;
    __half2 h23 = *(__half2*)&raw.y;
    float2 f01 = __half22float2(h01);
    float2 f23 = __half22float2(h23);
    return make_float4(f01.x, f01.y, f23.x, f23.y);
}

__device__ __forceinline__ float u2f(unsigned u) {
    union { unsigned u; float f; } c; c.u = u; return c.f;
}

// ---------------- degree / norm ----------------
__global__ void deg_count_kernel(const int* __restrict__ ei, int* __restrict__ deg) {
    int e = blockIdx.x * blockDim.x + threadIdx.x;
    if (e < N_EDGES) atomicAdd(&deg[ei[N_EDGES + e]], 1);
}

// ---------------- hierarchical scan (also emits dinv) ----------------
__global__ __launch_bounds__(256) void block_scan_kernel(const int* __restrict__ deg,
                                                         int* __restrict__ rowptr,
                                                         int* __restrict__ bsums,
                                                         float* __restrict__ dinv) {
    __shared__ int s[256];
    int tid = threadIdx.x;
    int i = blockIdx.x * 256 + tid;
    int v = (i < N_NODES) ? deg[i] : 0;
    if (i < N_NODES) dinv[i] = rsqrtf((float)(v + 1)); // +1 = self loop
    s[tid] = v;
    __syncthreads();
#pragma unroll
    for (int ofs = 1; ofs < 256; ofs <<= 1) {
        int t = (tid >= ofs) ? s[tid - ofs] : 0;
        __syncthreads();
        s[tid] += t;
        __syncthreads();
    }
    if (i < N_NODES) rowptr[i + 1] = s[tid];
    if (tid == 255) bsums[blockIdx.x] = s[255];
}

__global__ __launch_bounds__(256) void scan_bsums_kernel(int* __restrict__ bsums, int nb) {
    __shared__ int s[256];
    int tid = threadIdx.x;
    int v = (tid < nb) ? bsums[tid] : 0;
    s[tid] = v;
    __syncthreads();
#pragma unroll
    for (int ofs = 1; ofs < 256; ofs <<= 1) {
        int t = (tid >= ofs) ? s[tid - ofs] : 0;
        __syncthreads();
        s[tid] += t;
        __syncthreads();
    }
    if (tid < nb) bsums[tid] = (tid == 0) ? 0 : s[tid - 1];
}

__global__ __launch_bounds__(256) void add_offsets_kernel(int* __restrict__ rowptr,
                                                          const int* __restrict__ bsums) {
    int i = blockIdx.x * 256 + threadIdx.x;
    if (i == 0) rowptr[0] = 0;
    if (i < N_NODES) rowptr[i + 1] += bsums[blockIdx.x];
}

// CSR entry packed: .x = src index, .y = norm (float bits) — one 8B scatter per edge
__global__ void fill_csr_kernel(const int* __restrict__ ei, const int* __restrict__ rowptr,
                                int* __restrict__ cursor, const float* __restrict__ dinv,
                                uint2* __restrict__ csr) {
    int e = blockIdx.x * blockDim.x + threadIdx.x;
    if (e < N_EDGES) {
        int s = ei[e];
        int d = ei[N_EDGES + e];
        int p = rowptr[d] + atomicAdd(&cursor[d], 1);
        float w = dinv[s] * dinv[d];
        uint2 pk;
        pk.x = (unsigned)s;
        pk.y = *(unsigned*)&w;
        csr[p] = pk;
    }
}

// ---------------- conv1 stage A: aggregate 2-ch x ----------------
__global__ void aggx_kernel(const float* __restrict__ x, const int* __restrict__ rowptr,
                            const uint2* __restrict__ csr,
                            const float* __restrict__ dinv, float* __restrict__ ax) {
    int i = blockIdx.x * blockDim.x + threadIdx.x;
    if (i >= N_NODES) return;
    float di = dinv[i];
    float w0 = di * di;
    float2 xi = *(const float2*)&x[2 * i];
    float a0 = xi.x * w0, a1 = xi.y * w0;
    int e0 = rowptr[i], e1 = rowptr[i + 1];
    int p = e0;
    for (; p + 4 <= e1; p += 4) {
        uint2 e0v = csr[p + 0], e1v = csr[p + 1], e2v = csr[p + 2], e3v = csr[p + 3];
        float2 u0 = *(const float2*)&x[2 * e0v.x];
        float2 u1 = *(const float2*)&x[2 * e1v.x];
        float2 u2 = *(const float2*)&x[2 * e2v.x];
        float2 u3 = *(const float2*)&x[2 * e3v.x];
        float n0 = u2f(e0v.y), n1 = u2f(e1v.y), n2 = u2f(e2v.y), n3 = u2f(e3v.y);
        a0 += u0.x * n0 + u1.x * n1 + u2.x * n2 + u3.x * n3;
        a1 += u0.y * n0 + u1.y * n1 + u2.y * n2 + u3.y * n3;
    }
    for (; p < e1; ++p) {
        uint2 ev = csr[p];
        float w = u2f(ev.y);
        float2 u = *(const float2*)&x[2 * ev.x];
        a0 += u.x * w;
        a1 += u.y * w;
    }
    ax[2 * i] = a0;
    ax[2 * i + 1] = a1;
}

// ---------------- W split+transpose: WT[n][k] fp16 hi + fp16 lo residual ----------------
__global__ void wsplit_kernel(const float* __restrict__ W2, const float* __restrict__ W3,
                              const float* __restrict__ W4,
                              __half* __restrict__ whiT, __half* __restrict__ wloT) {
    int which = blockIdx.y;
    const float* W = (which == 0) ? W2 : ((which == 1) ? W3 : W4);
    __half* hT = whiT + which * 65536;
    __half* lT = wloT + which * 65536;
    int n = blockIdx.x, k = threadIdx.x;
    float v = W[k * 256 + n];
    __half h = __float2half_rn(v);
    float res = v - __half2float(h);
    hT[n * 256 + k] = h;
    lT[n * 256 + k] = __float2half_rn(res);
}

// ---- FUSE1 helper: compute r-row chunk = relu(ax0*W1[0,k..]+ax1*W1[1,k..]+b1[k..]) fp16 ----
__device__ __forceinline__ fp16x8 fuse1_chunk(float ax0, float ax1,
                                              const float* __restrict__ W1,
                                              const float* __restrict__ b1, int kcol) {
    fp16x8 out;
#pragma unroll
    for (int j = 0; j < 8; ++j) {
        float h = ax0 * W1[kcol + j] + ax1 * W1[256 + kcol + j] + b1[kcol + j];
        out[j] = (_Float16)fmaxf(h, 0.f);
    }
    return out;
}

// ---------------- MFMA GEMM: t = r @ (Whi + Wlo), all-fp16 operands ----------------
// LDS DOUBLE-BUFFERED K-loop: stage chunk k+1 into buf[1-p] while computing chunk k
// from buf[p] -> ONE barrier per chunk (was 2) and global prefetch latency overlapped
// with the MFMA block. Safety: buf[1-p]'s last reader was chunk k-1's compute, which
// every wave finished (program order) before this chunk's barrier.
// 128x256 tile, 8 waves of 64x64, 8 K-chunks of 32. LDS 80 KB -> 2 blocks/CU.
template <int FUSE1>
__global__ __launch_bounds__(512) void mfma_gemm_kernel(const __half* __restrict__ r,
                                                        const float* __restrict__ ax,
                                                        const float* __restrict__ W1,
                                                        const float* __restrict__ b1,
                                                        const __half* __restrict__ whiT,
                                                        const __half* __restrict__ wloT,
                                                        __half* __restrict__ t) {
    union SMem {
        struct {
            short Ah[2][128][32];  // 16 KB
            short Bh[2][256][32];  // 32 KB
            short Bl[2][256][32];  // 32 KB
        } s;
        __half c[64][260];         // 33.3 KB (64-row output staging)
    };
    __shared__ SMem sm;
    int tid = threadIdx.x;
    int row0 = blockIdx.x * 128;
    int lane = tid & 63;
    int wave = tid >> 6;          // 0..7
    int wm = wave & 1;            // row 64-tile
    int wn = wave >> 1;           // col 64-tile (0..3)
    int wq = lane >> 4, lm = lane & 15;

    // A staging: thread -> row tid>>2 (0..127), quad tid&3 (8 fp16 = 16B)
    int arow = tid >> 2;
    int aq = tid & 3;
    int ga = row0 + arow; if (ga >= N_NODES) ga = N_NODES - 1; // clamp; rows never stored
    size_t abase = (size_t)ga * 256 + aq * 8;
    int aswz = (aq ^ (arow & 3)) * 8;

    float ax0 = 0.f, ax1 = 0.f;
    if (FUSE1) {
        float2 axv = *(const float2*)&ax[2 * ga];
        ax0 = axv.x; ax1 = axv.y;
    }

    // B staging: thread -> col tid>>1 (0..255), quads {2h, 2h+1} of Bh and Bl
    int bcol = tid >> 1;
    int bh = (tid & 1) * 2;
    size_t bbase = (size_t)bcol * 256 + bh * 8;
    int bswz0 = ((bh + 0) ^ (bcol & 3)) * 8;
    int bswz1 = ((bh + 1) ^ (bcol & 3)) * 8;

    f32x4 acc[4][4];
#pragma unroll
    for (int mi = 0; mi < 4; ++mi)
#pragma unroll
        for (int ni = 0; ni < 4; ++ni) acc[mi][ni] = (f32x4)0.f;

    // prefetch chunk 0 and stage into buf 0 (reads gated by first barrier)
    {
        fp16x8 a0;
        if (FUSE1) a0 = fuse1_chunk(ax0, ax1, W1, b1, aq * 8);
        else       a0 = *(const fp16x8*)(r + abase);
        uint4 bh0 = *(const uint4*)(whiT + bbase);
        uint4 bh1 = *(const uint4*)(whiT + bbase + 8);
        uint4 bl0 = *(const uint4*)(wloT + bbase);
        uint4 bl1 = *(const uint4*)(wloT + bbase + 8);
        *(fp16x8*)&sm.s.Ah[0][arow][aswz] = a0;
        *(uint4*)&sm.s.Bh[0][bcol][bswz0] = bh0;
        *(uint4*)&sm.s.Bh[0][bcol][bswz1] = bh1;
        *(uint4*)&sm.s.Bl[0][bcol][bswz0] = bl0;
        *(uint4*)&sm.s.Bl[0][bcol][bswz1] = bl1;
    }

    int pfr = ((wq ^ (lm & 3)) * 8); // swizzled fragment read column

    for (int cc = 0; cc < 8; ++cc) {
        int cur = cc & 1;
        __syncthreads();   // buf[cur] staged; buf[1-cur]'s prior readers all done

        // issue global prefetch for chunk cc+1 (consumed by LDS writes at body end)
        fp16x8 a0;
        uint4 bh0, bh1, bl0, bl1;
        if (cc + 1 < 8) {
            int kk = (cc + 1) * 32;
            if (FUSE1) a0 = fuse1_chunk(ax0, ax1, W1, b1, kk + aq * 8);
            else       a0 = *(const fp16x8*)(r + abase + kk);
            bh0 = *(const uint4*)(whiT + bbase + kk);
            bh1 = *(const uint4*)(whiT + bbase + kk + 8);
            bl0 = *(const uint4*)(wloT + bbase + kk);
            bl1 = *(const uint4*)(wloT + bbase + kk + 8);
        }

        // compute chunk cc from buf[cur]
        fp16x8 af[4], bfh[4], bfl[4];
#pragma unroll
        for (int mi = 0; mi < 4; ++mi)
            af[mi] = *(const fp16x8*)&sm.s.Ah[cur][wm * 64 + mi * 16 + lm][pfr];
#pragma unroll
        for (int ni = 0; ni < 4; ++ni) {
            bfh[ni] = *(const fp16x8*)&sm.s.Bh[cur][wn * 64 + ni * 16 + lm][pfr];
            bfl[ni] = *(const fp16x8*)&sm.s.Bl[cur][wn * 64 + ni * 16 + lm][pfr];
        }
#pragma unroll
        for (int mi = 0; mi < 4; ++mi)
#pragma unroll
            for (int ni = 0; ni < 4; ++ni) {
                acc[mi][ni] = __builtin_amdgcn_mfma_f32_16x16x32_f16(af[mi], bfh[ni],
                                                                     acc[mi][ni], 0, 0, 0);
                acc[mi][ni] = __builtin_amdgcn_mfma_f32_16x16x32_f16(af[mi], bfl[ni],
                                                                     acc[mi][ni], 0, 0, 0);
            }

        // stage chunk cc+1 into the other buffer (no barrier needed before next iter's)
        if (cc + 1 < 8) {
            *(fp16x8*)&sm.s.Ah[1 - cur][arow][aswz] = a0;
            *(uint4*)&sm.s.Bh[1 - cur][bcol][bswz0] = bh0;
            *(uint4*)&sm.s.Bh[1 - cur][bcol][bswz1] = bh1;
            *(uint4*)&sm.s.Bl[1 - cur][bcol][bswz0] = bl0;
            *(uint4*)&sm.s.Bl[1 - cur][bcol][bswz1] = bl1;
        }
    }

    // epilogue: two 64-row halves through the LDS tile (union), coalesced 512B-row stores
#pragma unroll
    for (int half = 0; half < 2; ++half) {
        __syncthreads();
        if (wm == half) {
#pragma unroll
            for (int mi = 0; mi < 4; ++mi) {
                int rb = mi * 16 + wq * 4;
#pragma unroll
                for (int ni = 0; ni < 4; ++ni) {
                    int cb = wn * 64 + ni * 16 + lm;
#pragma unroll
                    for (int rr = 0; rr < 4; ++rr)
                        sm.c[rb + rr][cb] = __float2half(acc[mi][ni][rr]);
                }
            }
        }
        __syncthreads();
#pragma unroll
        for (int pass = 0; pass < 4; ++pass) {
            int row = pass * 16 + (tid >> 5);
            int gr = row0 + half * 64 + row;
            int ch = tid & 31;
            if (gr < N_NODES)
                *(uint4*)(t + (size_t)gr * 256 + ch * 8) = *(const uint4*)&sm.c[row][ch * 8];
        }
    }
}

// ---------------- full-row aggregation (layers 2,3), wave per node ----------------
__global__ __launch_bounds__(256) void agg_full_kernel(const __half* __restrict__ t,
                                                       const int* __restrict__ rowptr,
                                                       const uint2* __restrict__ csr,
                                                       const float* __restrict__ dinv,
                                                       const float* __restrict__ bias,
                                                       __half* __restrict__ rout) {
    int node = blockIdx.x * 4 + (threadIdx.x >> 6);
    if (node >= N_NODES) return;
    int lane = threadIdx.x & 63;
    int c = lane * 4;
    float di = dinv[node];
    float w0 = di * di;
    float4 v = h8load(t + (size_t)node * HIDDEN + c);
    float4 acc = make_float4(v.x * w0, v.y * w0, v.z * w0, v.w * w0);
    int e0 = rowptr[node], e1 = rowptr[node + 1];
    int p = e0;
    for (; p + 4 <= e1; p += 4) {
        uint2 ev0 = csr[p + 0], ev1 = csr[p + 1], ev2 = csr[p + 2], ev3 = csr[p + 3];
        float n0 = u2f(ev0.y), n1 = u2f(ev1.y), n2 = u2f(ev2.y), n3 = u2f(ev3.y);
        float4 u0 = h8load(t + (size_t)ev0.x * HIDDEN + c);
        float4 u1 = h8load(t + (size_t)ev1.x * HIDDEN + c);
        float4 u2 = h8load(t + (size_t)ev2.x * HIDDEN + c);
        float4 u3 = h8load(t + (size_t)ev3.x * HIDDEN + c);
        acc.x += u0.x * n0; acc.y += u0.y * n0; acc.z += u0.z * n0; acc.w += u0.w * n0;
        acc.x += u1.x * n1; acc.y += u1.y * n1; acc.z += u1.z * n1; acc.w += u1.w * n1;
        acc.x += u2.x * n2; acc.y += u2.y * n2; acc.z += u2.z * n2; acc.w += u2.w * n2;
        acc.x += u3.x * n3; acc.y += u3.y * n3; acc.z += u3.z * n3; acc.w += u3.w * n3;
    }
    for (; p < e1; ++p) {
        uint2 ev = csr[p];
        float w = u2f(ev.y);
        float4 u = h8load(t + (size_t)ev.x * HIDDEN + c);
        acc.x += u.x * w; acc.y += u.y * w; acc.z += u.z * w; acc.w += u.w * w;
    }
    float4 b4 = *(const float4*)&bias[c];
    acc.x += b4.x; acc.y += b4.y; acc.z += b4.z; acc.w += b4.w;

    __half2 h01 = __floats2half2_rn(fmaxf(acc.x, 0.f), fmaxf(acc.y, 0.f));
    __half2 h23 = __floats2half2_rn(fmaxf(acc.z, 0.f), fmaxf(acc.w, 0.f));
    uint2 pk;
    pk.x = *(unsigned*)&h01;
    pk.y = *(unsigned*)&h23;
    *(uint2*)&rout[(size_t)node * HIDDEN + c] = pk;
}

// ---------------- fused layer-4 aggregation + mean-pool, node-parallel ----------------
__global__ __launch_bounds__(256) void agg_pool2_kernel(const __half* __restrict__ t,
                                                        const int* __restrict__ rowptr,
                                                        const uint2* __restrict__ csr,
                                                        const float* __restrict__ dinv,
                                                        const int* __restrict__ batch,
                                                        float* __restrict__ gsum) {
    __shared__ float buf[4][256];
    __shared__ int gids[4];
    int wave = threadIdx.x >> 6;
    int lane = threadIdx.x & 63;
    int node = blockIdx.x * 4 + wave;
    int c = lane * 4;

    if (node < N_NODES) {
        float di = dinv[node];
        float w0 = di * di;
        float4 v = h8load(t + (size_t)node * HIDDEN + c);
        float4 acc = make_float4(v.x * w0, v.y * w0, v.z * w0, v.w * w0);
        int e0 = rowptr[node], e1 = rowptr[node + 1];
        int p = e0;
        for (; p + 4 <= e1; p += 4) {
            uint2 ev0 = csr[p + 0], ev1 = csr[p + 1], ev2 = csr[p + 2], ev3 = csr[p + 3];
            float n0 = u2f(ev0.y), n1 = u2f(ev1.y), n2 = u2f(ev2.y), n3 = u2f(ev3.y);
            float4 u0 = h8load(t + (size_t)ev0.x * HIDDEN + c);
            float4 u1 = h8load(t + (size_t)ev1.x * HIDDEN + c);
            float4 u2 = h8load(t + (size_t)ev2.x * HIDDEN + c);
            float4 u3 = h8load(t + (size_t)ev3.x * HIDDEN + c);
            acc.x += u0.x * n0; acc.y += u0.y * n0; acc.z += u0.z * n0; acc.w += u0.w * n0;
            acc.x += u1.x * n1; acc.y += u1.y * n1; acc.z += u1.z * n1; acc.w += u1.w * n1;
            acc.x += u2.x * n2; acc.y += u2.y * n2; acc.z += u2.z * n2; acc.w += u2.w * n2;
            acc.x += u3.x * n3; acc.y += u3.y * n3; acc.z += u3.z * n3; acc.w += u3.w * n3;
        }
        for (; p < e1; ++p) {
            uint2 ev = csr[p];
            float w = u2f(ev.y);
            float4 u = h8load(t + (size_t)ev.x * HIDDEN + c);
            acc.x += u.x * w; acc.y += u.y * w; acc.z += u.z * w; acc.w += u.w * w;
        }
        *(float4*)&buf[wave][c] = acc;
        if (lane == 0) gids[wave] = batch[node];
    } else {
        if (lane == 0) gids[wave] = -1;
    }
    __syncthreads();

    // segmented add: thread ch = threadIdx.x handles one channel across the 4 rows
    int ch = threadIdx.x;
    float s = 0.f;
    int cur = -1;
#pragma unroll
    for (int w = 0; w < 4; ++w) {
        int gw = gids[w];
        if (gw < 0) continue;
        if (gw != cur) {
            if (cur >= 0) atomicAdd(&gsum[cur * HIDDEN + ch], s);
            cur = gw;
            s = 0.f;
        }
        s += buf[w][ch];
    }
    if (cur >= 0) atomicAdd(&gsum[cur * HIDDEN + ch], s);
}

// ---------------- pooling bounds ----------------
__global__ void bounds_kernel(const int* __restrict__ batch, int* __restrict__ gbounds) {
    int i = blockIdx.x * blockDim.x + threadIdx.x;
    if (i >= N_NODES) return;
    int bi = batch[i];
    int bprev = (i == 0) ? -1 : batch[i - 1];
    for (int g = bprev + 1; g <= bi; ++g) gbounds[g] = i;
    if (i == N_NODES - 1) {
        for (int g = bi + 1; g <= N_GRAPHS; ++g) gbounds[g] = N_NODES;
    }
}

// ---------------- MLP head (folds mean-divide + b4) ----------------
__global__ __launch_bounds__(128) void mlp_kernel(const float* __restrict__ gsum,
                                                  const int* __restrict__ gbounds,
                                                  const float* __restrict__ b4,
                                                  const float* __restrict__ lin1_w,
                                                  const float* __restrict__ lin1_b,
                                                  const float* __restrict__ lin2_w,
                                                  const float* __restrict__ lin2_b,
                                                  float* __restrict__ out) {
    __shared__ float grow[HIDDEN];
    __shared__ float red[2];
    int g = blockIdx.x, j = threadIdx.x;
    int cnt = gbounds[g + 1] - gbounds[g];
    float inv = 1.f / fmaxf((float)cnt, 1.f);
    float bb = (cnt > 0) ? 1.f : 0.f;
    grow[j] = gsum[g * HIDDEN + j] * inv + b4[j] * bb;
    grow[j + 128] = gsum[g * HIDDEN + j + 128] * inv + b4[j + 128] * bb;
    __syncthreads();
    float acc = lin1_b[j];
    for (int k = 0; k < HIDDEN; ++k) acc += grow[k] * lin1_w[k * 128 + j];
    acc = fmaxf(acc, 0.f);
    float v = acc * lin2_w[j];
#pragma unroll
    for (int ofs = 32; ofs > 0; ofs >>= 1) v += __shfl_down(v, ofs, 64);
    if ((j & 63) == 0) red[j >> 6] = v;
    __syncthreads();
    if (j == 0) out[g] = red[0] + red[1] + lin2_b[0];
}

// ---------------- launch ----------------
extern "C" void kernel_launch(void* const* d_in, const int* in_sizes, int n_in,
                              void* d_out, int out_size, void* d_ws, size_t ws_size,
                              hipStream_t stream) {
    const float* x      = (const float*)d_in[0];
    const int*   ei     = (const int*)d_in[1];
    const int*   batch  = (const int*)d_in[2];
    const float* W1     = (const float*)d_in[3];
    const float* b1     = (const float*)d_in[4];
    const float* W2     = (const float*)d_in[5];
    const float* b2     = (const float*)d_in[6];
    const float* W3     = (const float*)d_in[7];
    const float* b3     = (const float*)d_in[8];
    const float* W4     = (const float*)d_in[9];
    const float* b4     = (const float*)d_in[10];
    const float* lin1_w = (const float*)d_in[11];
    const float* lin1_b = (const float*)d_in[12];
    const float* lin2_w = (const float*)d_in[13];
    const float* lin2_b = (const float*)d_in[14];
    float* out = (float*)d_out;

    char* ws = (char*)d_ws;
    size_t off = 0;
    auto alloc = [&](size_t bytes) -> void* {
        void* p = ws + off;
        off += (bytes + 255) & ~(size_t)255;
        return p;
    };
    __half* tbuf = (__half*)alloc((size_t)N_NODES * HIDDEN * 2);  // 25.6 MB fp16 (GEMM out)
    __half* rbuf = (__half*)alloc((size_t)N_NODES * HIDDEN * 2);  // 25.6 MB fp16 (GEMM in)
    uint2* csr      = (uint2*)alloc((size_t)N_EDGES * 8);
    int*   rowptr   = (int*)alloc((size_t)(N_NODES + 1) * 4);
    int*   deg      = (int*)alloc((size_t)N_NODES * 4);
    int*   cursor   = (int*)alloc((size_t)N_NODES * 4);
    float* dinv     = (float*)alloc((size_t)N_NODES * 4);
    float* ax       = (float*)alloc((size_t)N_NODES * 2 * 4);
    float* gsum     = (float*)alloc((size_t)N_GRAPHS * HIDDEN * 4);
    int*   gbounds  = (int*)alloc((size_t)(N_GRAPHS + 1) * 4);
    int*   bsums    = (int*)alloc((size_t)256 * 4);
    __half* whiT = (__half*)alloc((size_t)3 * 65536 * 2);
    __half* wloT = (__half*)alloc((size_t)3 * 65536 * 2);

    hipMemsetAsync(deg, 0, (size_t)N_NODES * 4, stream);
    hipMemsetAsync(cursor, 0, (size_t)N_NODES * 4, stream);
    hipMemsetAsync(gsum, 0, (size_t)N_GRAPHS * HIDDEN * 4, stream);

    const int TB = 256;
    const int NBLK = (N_NODES + 255) / 256;
    deg_count_kernel<<<(N_EDGES + TB - 1) / TB, TB, 0, stream>>>(ei, deg);
    block_scan_kernel<<<NBLK, 256, 0, stream>>>(deg, rowptr, bsums, dinv);
    scan_bsums_kernel<<<1, 256, 0, stream>>>(bsums, NBLK);
    add_offsets_kernel<<<NBLK, 256, 0, stream>>>(rowptr, bsums);
    fill_csr_kernel<<<(N_EDGES + TB - 1) / TB, TB, 0, stream>>>(ei, rowptr, cursor, dinv, csr);
    wsplit_kernel<<<dim3(256, 3), 256, 0, stream>>>(W2, W3, W4, whiT, wloT);
    bounds_kernel<<<(N_NODES + TB - 1) / TB, TB, 0, stream>>>(batch, gbounds);

    // conv1 stage A: ax = (A x)
    aggx_kernel<<<(N_NODES + TB - 1) / TB, TB, 0, stream>>>(x, rowptr, csr, dinv, ax);

    // conv2..4 (layer-2 GEMM fuses the conv1 expand)
    const int NGB = (N_NODES + 127) / 128;
    const int NAGG = (N_NODES + 3) / 4;
    mfma_gemm_kernel<1><<<NGB, 512, 0, stream>>>(nullptr, ax, W1, b1,
                                                 whiT + 0 * 65536, wloT + 0 * 65536, tbuf);
    agg_full_kernel<<<NAGG, 256, 0, stream>>>(tbuf, rowptr, csr, dinv, b2, rbuf);
    mfma_gemm_kernel<0><<<NGB, 512, 0, stream>>>(rbuf, nullptr, nullptr, nullptr,
                                                 whiT + 1 * 65536, wloT + 1 * 65536, tbuf);
    agg_full_kernel<<<NAGG, 256, 0, stream>>>(tbuf, rowptr, csr, dinv, b3, rbuf);
    mfma_gemm_kernel<0><<<NGB, 512, 0, stream>>>(rbuf, nullptr, nullptr, nullptr,
                                                 whiT + 2 * 65536, wloT + 2 * 65536, tbuf);
    agg_pool2_kernel<<<NAGG, 256, 0, stream>>>(tbuf, rowptr, csr, dinv, batch, gsum);

    // head
    mlp_kernel<<<N_GRAPHS, 128, 0, stream>>>(gsum, gbounds, b4, lin1_w, lin1_b,
                                             lin2_w, lin2_b, out);
}

// Round 14
// 451.755 us; speedup vs baseline: 1.0186x; 1.0186x over previous
//
#include <hip/hip_runtime.h>
#include <hip/hip_bf16.h>
#include <hip/hip_fp16.h>

#define N_NODES 50000
#define N_EDGES 800000
#define HIDDEN  256
#define N_GRAPHS 128

typedef _Float16 fp16x8 __attribute__((ext_vector_type(8)));
typedef float f32x4 __attribute__((ext_vector_type(4)));

// ---- fp16x4 row-chunk load + convert ----
__device__ __forceinline__ float4 h8load(const __half* p) {
    uint2 raw = *(const uint2*)p;
    __half2 h01 = *(__half2*)&raw.x;
    __half2 h23 = *(__half2*)&raw.y;
    float2 f01 = __half22float2(h01);
    float2 f23 = __half22float2(h23);
    return make_float4(f01.x, f01.y, f23.x, f23.y);
}

__device__ __forceinline__ float u2f(unsigned u) {
    union { unsigned u; float f; } c; c.u = u; return c.f;
}

// ---------------- degree / norm ----------------
__global__ void deg_count_kernel(const int* __restrict__ ei, int* __restrict__ deg) {
    int e = blockIdx.x * blockDim.x + threadIdx.x;
    if (e < N_EDGES) atomicAdd(&deg[ei[N_EDGES + e]], 1);
}

// ---------------- hierarchical scan (also emits dinv) ----------------
__global__ __launch_bounds__(256) void block_scan_kernel(const int* __restrict__ deg,
                                                         int* __restrict__ rowptr,
                                                         int* __restrict__ bsums,
                                                         float* __restrict__ dinv) {
    __shared__ int s[256];
    int tid = threadIdx.x;
    int i = blockIdx.x * 256 + tid;
    int v = (i < N_NODES) ? deg[i] : 0;
    if (i < N_NODES) dinv[i] = rsqrtf((float)(v + 1)); // +1 = self loop
    s[tid] = v;
    __syncthreads();
#pragma unroll
    for (int ofs = 1; ofs < 256; ofs <<= 1) {
        int t = (tid >= ofs) ? s[tid - ofs] : 0;
        __syncthreads();
        s[tid] += t;
        __syncthreads();
    }
    if (i < N_NODES) rowptr[i + 1] = s[tid];
    if (tid == 255) bsums[blockIdx.x] = s[255];
}

__global__ __launch_bounds__(256) void scan_bsums_kernel(int* __restrict__ bsums, int nb) {
    __shared__ int s[256];
    int tid = threadIdx.x;
    int v = (tid < nb) ? bsums[tid] : 0;
    s[tid] = v;
    __syncthreads();
#pragma unroll
    for (int ofs = 1; ofs < 256; ofs <<= 1) {
        int t = (tid >= ofs) ? s[tid - ofs] : 0;
        __syncthreads();
        s[tid] += t;
        __syncthreads();
    }
    if (tid < nb) bsums[tid] = (tid == 0) ? 0 : s[tid - 1];
}

__global__ __launch_bounds__(256) void add_offsets_kernel(int* __restrict__ rowptr,
                                                          const int* __restrict__ bsums) {
    int i = blockIdx.x * 256 + threadIdx.x;
    if (i == 0) rowptr[0] = 0;
    if (i < N_NODES) rowptr[i + 1] += bsums[blockIdx.x];
}

// CSR entry packed: .x = src index, .y = norm (float bits) — one 8B scatter per edge
__global__ void fill_csr_kernel(const int* __restrict__ ei, const int* __restrict__ rowptr,
                                int* __restrict__ cursor, const float* __restrict__ dinv,
                                uint2* __restrict__ csr) {
    int e = blockIdx.x * blockDim.x + threadIdx.x;
    if (e < N_EDGES) {
        int s = ei[e];
        int d = ei[N_EDGES + e];
        int p = rowptr[d] + atomicAdd(&cursor[d], 1);
        float w = dinv[s] * dinv[d];
        uint2 pk;
        pk.x = (unsigned)s;
        pk.y = *(unsigned*)&w;
        csr[p] = pk;
    }
}

// ---------------- conv1 stage A: aggregate 2-ch x ----------------
__global__ void aggx_kernel(const float* __restrict__ x, const int* __restrict__ rowptr,
                            const uint2* __restrict__ csr,
                            const float* __restrict__ dinv, float* __restrict__ ax) {
    int i = blockIdx.x * blockDim.x + threadIdx.x;
    if (i >= N_NODES) return;
    float di = dinv[i];
    float w0 = di * di;
    float2 xi = *(const float2*)&x[2 * i];
    float a0 = xi.x * w0, a1 = xi.y * w0;
    int e0 = rowptr[i], e1 = rowptr[i + 1];
    int p = e0;
    for (; p + 4 <= e1; p += 4) {
        uint2 e0v = csr[p + 0], e1v = csr[p + 1], e2v = csr[p + 2], e3v = csr[p + 3];
        float2 u0 = *(const float2*)&x[2 * e0v.x];
        float2 u1 = *(const float2*)&x[2 * e1v.x];
        float2 u2 = *(const float2*)&x[2 * e2v.x];
        float2 u3 = *(const float2*)&x[2 * e3v.x];
        float n0 = u2f(e0v.y), n1 = u2f(e1v.y), n2 = u2f(e2v.y), n3 = u2f(e3v.y);
        a0 += u0.x * n0 + u1.x * n1 + u2.x * n2 + u3.x * n3;
        a1 += u0.y * n0 + u1.y * n1 + u2.y * n2 + u3.y * n3;
    }
    for (; p < e1; ++p) {
        uint2 ev = csr[p];
        float w = u2f(ev.y);
        float2 u = *(const float2*)&x[2 * ev.x];
        a0 += u.x * w;
        a1 += u.y * w;
    }
    ax[2 * i] = a0;
    ax[2 * i + 1] = a1;
}

// ---------------- W split+transpose: WT[n][k] fp16 hi + fp16 lo residual ----------------
__global__ void wsplit_kernel(const float* __restrict__ W2, const float* __restrict__ W3,
                              const float* __restrict__ W4,
                              __half* __restrict__ whiT, __half* __restrict__ wloT) {
    int which = blockIdx.y;
    const float* W = (which == 0) ? W2 : ((which == 1) ? W3 : W4);
    __half* hT = whiT + which * 65536;
    __half* lT = wloT + which * 65536;
    int n = blockIdx.x, k = threadIdx.x;
    float v = W[k * 256 + n];
    __half h = __float2half_rn(v);
    float res = v - __half2float(h);
    hT[n * 256 + k] = h;
    lT[n * 256 + k] = __float2half_rn(res);
}

// ---- FUSE1 helper: compute r-row chunk = relu(ax0*W1[0,k..]+ax1*W1[1,k..]+b1[k..]) fp16 ----
__device__ __forceinline__ fp16x8 fuse1_chunk(float ax0, float ax1,
                                              const float* __restrict__ W1,
                                              const float* __restrict__ b1, int kcol) {
    fp16x8 out;
#pragma unroll
    for (int j = 0; j < 8; ++j) {
        float h = ax0 * W1[kcol + j] + ax1 * W1[256 + kcol + j] + b1[kcol + j];
        out[j] = (_Float16)fmaxf(h, 0.f);
    }
    return out;
}

// ---------------- MFMA GEMM: t = r @ (Whi + Wlo), all-fp16 operands (R12 version) ----------------
// Single-buffered 2-barrier K-loop at FULL occupancy (40KB LDS -> 4 blocks/CU = 32 waves/CU).
// R13's double-buffer (80KB, 2 blocks/CU) measured WORSE (460 vs 456) — implicit wave-level
// overlap at max occupancy beats explicit pipelining on this structure (matches learn_hip m99/m100).
// 128x256 tile, 8 waves of 64x64, 8 K-chunks of 32, 32 f16-MFMA/wave/chunk.
// LDS stride 32 shorts, XOR quad swizzle. 64-row output staging.
template <int FUSE1>
__global__ __launch_bounds__(512) void mfma_gemm_kernel(const __half* __restrict__ r,
                                                        const float* __restrict__ ax,
                                                        const float* __restrict__ W1,
                                                        const float* __restrict__ b1,
                                                        const __half* __restrict__ whiT,
                                                        const __half* __restrict__ wloT,
                                                        __half* __restrict__ t) {
    union SMem {
        struct {
            short Ah[128][32];  //  8 KB
            short Bh[256][32];  // 16 KB
            short Bl[256][32];  // 16 KB
        } s;
        __half c[64][260];      // 33.3 KB (64-row output staging)
    };
    __shared__ SMem sm;
    int tid = threadIdx.x;
    int row0 = blockIdx.x * 128;
    int lane = tid & 63;
    int wave = tid >> 6;          // 0..7
    int wm = wave & 1;            // row 64-tile
    int wn = wave >> 1;           // col 64-tile (0..3)
    int wq = lane >> 4, lm = lane & 15;

    // A staging: thread -> row tid>>2 (0..127), quad tid&3 (8 fp16 = 16B)
    int arow = tid >> 2;
    int aq = tid & 3;
    int ga = row0 + arow; if (ga >= N_NODES) ga = N_NODES - 1; // clamp; rows never stored
    size_t abase = (size_t)ga * 256 + aq * 8;
    int aswz = (aq ^ (arow & 3)) * 8;

    float ax0 = 0.f, ax1 = 0.f;
    if (FUSE1) {
        float2 axv = *(const float2*)&ax[2 * ga];
        ax0 = axv.x; ax1 = axv.y;
    }

    // B staging: thread -> col tid>>1 (0..255), quads {2h, 2h+1} of Bh and Bl
    int bcol = tid >> 1;
    int bh = (tid & 1) * 2;
    size_t bbase = (size_t)bcol * 256 + bh * 8;
    int bswz0 = ((bh + 0) ^ (bcol & 3)) * 8;
    int bswz1 = ((bh + 1) ^ (bcol & 3)) * 8;

    f32x4 acc[4][4];
#pragma unroll
    for (int mi = 0; mi < 4; ++mi)
#pragma unroll
        for (int ni = 0; ni < 4; ++ni) acc[mi][ni] = (f32x4)0.f;

    // prefetch chunk 0
    fp16x8 a0;
    if (FUSE1) a0 = fuse1_chunk(ax0, ax1, W1, b1, aq * 8);
    else       a0 = *(const fp16x8*)(r + abase);
    uint4 bh0 = *(const uint4*)(whiT + bbase);
    uint4 bh1 = *(const uint4*)(whiT + bbase + 8);
    uint4 bl0 = *(const uint4*)(wloT + bbase);
    uint4 bl1 = *(const uint4*)(wloT + bbase + 8);

    int pfr = ((wq ^ (lm & 3)) * 8); // swizzled fragment read column

    for (int cc = 0; cc < 8; ++cc) {
        __syncthreads();
        *(fp16x8*)&sm.s.Ah[arow][aswz] = a0;
        *(uint4*)&sm.s.Bh[bcol][bswz0] = bh0;
        *(uint4*)&sm.s.Bh[bcol][bswz1] = bh1;
        *(uint4*)&sm.s.Bl[bcol][bswz0] = bl0;
        *(uint4*)&sm.s.Bl[bcol][bswz1] = bl1;
        __syncthreads();
        if (cc + 1 < 8) {
            int kk = (cc + 1) * 32;
            if (FUSE1) a0 = fuse1_chunk(ax0, ax1, W1, b1, kk + aq * 8);
            else       a0 = *(const fp16x8*)(r + abase + kk);
            bh0 = *(const uint4*)(whiT + bbase + kk);
            bh1 = *(const uint4*)(whiT + bbase + kk + 8);
            bl0 = *(const uint4*)(wloT + bbase + kk);
            bl1 = *(const uint4*)(wloT + bbase + kk + 8);
        }
        fp16x8 af[4], bfh[4], bfl[4];
#pragma unroll
        for (int mi = 0; mi < 4; ++mi)
            af[mi] = *(const fp16x8*)&sm.s.Ah[wm * 64 + mi * 16 + lm][pfr];
#pragma unroll
        for (int ni = 0; ni < 4; ++ni) {
            bfh[ni] = *(const fp16x8*)&sm.s.Bh[wn * 64 + ni * 16 + lm][pfr];
            bfl[ni] = *(const fp16x8*)&sm.s.Bl[wn * 64 + ni * 16 + lm][pfr];
        }
#pragma unroll
        for (int mi = 0; mi < 4; ++mi)
#pragma unroll
            for (int ni = 0; ni < 4; ++ni) {
                acc[mi][ni] = __builtin_amdgcn_mfma_f32_16x16x32_f16(af[mi], bfh[ni],
                                                                     acc[mi][ni], 0, 0, 0);
                acc[mi][ni] = __builtin_amdgcn_mfma_f32_16x16x32_f16(af[mi], bfl[ni],
                                                                     acc[mi][ni], 0, 0, 0);
            }
    }

    // epilogue: two 64-row halves through the 33KB LDS tile, coalesced 512B-row stores
#pragma unroll
    for (int half = 0; half < 2; ++half) {
        __syncthreads();
        if (wm == half) {
#pragma unroll
            for (int mi = 0; mi < 4; ++mi) {
                int rb = mi * 16 + wq * 4;
#pragma unroll
                for (int ni = 0; ni < 4; ++ni) {
                    int cb = wn * 64 + ni * 16 + lm;
#pragma unroll
                    for (int rr = 0; rr < 4; ++rr)
                        sm.c[rb + rr][cb] = __float2half(acc[mi][ni][rr]);
                }
            }
        }
        __syncthreads();
#pragma unroll
        for (int pass = 0; pass < 4; ++pass) {
            int row = pass * 16 + (tid >> 5);
            int gr = row0 + half * 64 + row;
            int ch = tid & 31;
            if (gr < N_NODES)
                *(uint4*)(t + (size_t)gr * 256 + ch * 8) = *(const uint4*)&sm.c[row][ch * 8];
        }
    }
}

// ---------------- full-row aggregation (layers 2,3), wave per node ----------------
__global__ __launch_bounds__(256) void agg_full_kernel(const __half* __restrict__ t,
                                                       const int* __restrict__ rowptr,
                                                       const uint2* __restrict__ csr,
                                                       const float* __restrict__ dinv,
                                                       const float* __restrict__ bias,
                                                       __half* __restrict__ rout) {
    int node = blockIdx.x * 4 + (threadIdx.x >> 6);
    if (node >= N_NODES) return;
    int lane = threadIdx.x & 63;
    int c = lane * 4;
    float di = dinv[node];
    float w0 = di * di;
    float4 v = h8load(t + (size_t)node * HIDDEN + c);
    float4 acc = make_float4(v.x * w0, v.y * w0, v.z * w0, v.w * w0);
    int e0 = rowptr[node], e1 = rowptr[node + 1];
    int p = e0;
    for (; p + 4 <= e1; p += 4) {
        uint2 ev0 = csr[p + 0], ev1 = csr[p + 1], ev2 = csr[p + 2], ev3 = csr[p + 3];
        float n0 = u2f(ev0.y), n1 = u2f(ev1.y), n2 = u2f(ev2.y), n3 = u2f(ev3.y);
        float4 u0 = h8load(t + (size_t)ev0.x * HIDDEN + c);
        float4 u1 = h8load(t + (size_t)ev1.x * HIDDEN + c);
        float4 u2 = h8load(t + (size_t)ev2.x * HIDDEN + c);
        float4 u3 = h8load(t + (size_t)ev3.x * HIDDEN + c);
        acc.x += u0.x * n0; acc.y += u0.y * n0; acc.z += u0.z * n0; acc.w += u0.w * n0;
        acc.x += u1.x * n1; acc.y += u1.y * n1; acc.z += u1.z * n1; acc.w += u1.w * n1;
        acc.x += u2.x * n2; acc.y += u2.y * n2; acc.z += u2.z * n2; acc.w += u2.w * n2;
        acc.x += u3.x * n3; acc.y += u3.y * n3; acc.z += u3.z * n3; acc.w += u3.w * n3;
    }
    for (; p < e1; ++p) {
        uint2 ev = csr[p];
        float w = u2f(ev.y);
        float4 u = h8load(t + (size_t)ev.x * HIDDEN + c);
        acc.x += u.x * w; acc.y += u.y * w; acc.z += u.z * w; acc.w += u.w * w;
    }
    float4 b4 = *(const float4*)&bias[c];
    acc.x += b4.x; acc.y += b4.y; acc.z += b4.z; acc.w += b4.w;

    __half2 h01 = __floats2half2_rn(fmaxf(acc.x, 0.f), fmaxf(acc.y, 0.f));
    __half2 h23 = __floats2half2_rn(fmaxf(acc.z, 0.f), fmaxf(acc.w, 0.f));
    uint2 pk;
    pk.x = *(unsigned*)&h01;
    pk.y = *(unsigned*)&h23;
    *(uint2*)&rout[(size_t)node * HIDDEN + c] = pk;
}

// ---------------- fused layer-4 aggregation + mean-pool, node-parallel ----------------
__global__ __launch_bounds__(256) void agg_pool2_kernel(const __half* __restrict__ t,
                                                        const int* __restrict__ rowptr,
                                                        const uint2* __restrict__ csr,
                                                        const float* __restrict__ dinv,
                                                        const int* __restrict__ batch,
                                                        float* __restrict__ gsum) {
    __shared__ float buf[4][256];
    __shared__ int gids[4];
    int wave = threadIdx.x >> 6;
    int lane = threadIdx.x & 63;
    int node = blockIdx.x * 4 + wave;
    int c = lane * 4;

    if (node < N_NODES) {
        float di = dinv[node];
        float w0 = di * di;
        float4 v = h8load(t + (size_t)node * HIDDEN + c);
        float4 acc = make_float4(v.x * w0, v.y * w0, v.z * w0, v.w * w0);
        int e0 = rowptr[node], e1 = rowptr[node + 1];
        int p = e0;
        for (; p + 4 <= e1; p += 4) {
            uint2 ev0 = csr[p + 0], ev1 = csr[p + 1], ev2 = csr[p + 2], ev3 = csr[p + 3];
            float n0 = u2f(ev0.y), n1 = u2f(ev1.y), n2 = u2f(ev2.y), n3 = u2f(ev3.y);
            float4 u0 = h8load(t + (size_t)ev0.x * HIDDEN + c);
            float4 u1 = h8load(t + (size_t)ev1.x * HIDDEN + c);
            float4 u2 = h8load(t + (size_t)ev2.x * HIDDEN + c);
            float4 u3 = h8load(t + (size_t)ev3.x * HIDDEN + c);
            acc.x += u0.x * n0; acc.y += u0.y * n0; acc.z += u0.z * n0; acc.w += u0.w * n0;
            acc.x += u1.x * n1; acc.y += u1.y * n1; acc.z += u1.z * n1; acc.w += u1.w * n1;
            acc.x += u2.x * n2; acc.y += u2.y * n2; acc.z += u2.z * n2; acc.w += u2.w * n2;
            acc.x += u3.x * n3; acc.y += u3.y * n3; acc.z += u3.z * n3; acc.w += u3.w * n3;
        }
        for (; p < e1; ++p) {
            uint2 ev = csr[p];
            float w = u2f(ev.y);
            float4 u = h8load(t + (size_t)ev.x * HIDDEN + c);
            acc.x += u.x * w; acc.y += u.y * w; acc.z += u.z * w; acc.w += u.w * w;
        }
        *(float4*)&buf[wave][c] = acc;
        if (lane == 0) gids[wave] = batch[node];
    } else {
        if (lane == 0) gids[wave] = -1;
    }
    __syncthreads();

    // segmented add: thread ch = threadIdx.x handles one channel across the 4 rows
    int ch = threadIdx.x;
    float s = 0.f;
    int cur = -1;
#pragma unroll
    for (int w = 0; w < 4; ++w) {
        int gw = gids[w];
        if (gw < 0) continue;
        if (gw != cur) {
            if (cur >= 0) atomicAdd(&gsum[cur * HIDDEN + ch], s);
            cur = gw;
            s = 0.f;
        }
        s += buf[w][ch];
    }
    if (cur >= 0) atomicAdd(&gsum[cur * HIDDEN + ch], s);
}

// ---------------- pooling bounds ----------------
__global__ void bounds_kernel(const int* __restrict__ batch, int* __restrict__ gbounds) {
    int i = blockIdx.x * blockDim.x + threadIdx.x;
    if (i >= N_NODES) return;
    int bi = batch[i];
    int bprev = (i == 0) ? -1 : batch[i - 1];
    for (int g = bprev + 1; g <= bi; ++g) gbounds[g] = i;
    if (i == N_NODES - 1) {
        for (int g = bi + 1; g <= N_GRAPHS; ++g) gbounds[g] = N_NODES;
    }
}

// ---------------- MLP head (folds mean-divide + b4) ----------------
__global__ __launch_bounds__(128) void mlp_kernel(const float* __restrict__ gsum,
                                                  const int* __restrict__ gbounds,
                                                  const float* __restrict__ b4,
                                                  const float* __restrict__ lin1_w,
                                                  const float* __restrict__ lin1_b,
                                                  const float* __restrict__ lin2_w,
                                                  const float* __restrict__ lin2_b,
                                                  float* __restrict__ out) {
    __shared__ float grow[HIDDEN];
    __shared__ float red[2];
    int g = blockIdx.x, j = threadIdx.x;
    int cnt = gbounds[g + 1] - gbounds[g];
    float inv = 1.f / fmaxf((float)cnt, 1.f);
    float bb = (cnt > 0) ? 1.f : 0.f;
    grow[j] = gsum[g * HIDDEN + j] * inv + b4[j] * bb;
    grow[j + 128] = gsum[g * HIDDEN + j + 128] * inv + b4[j + 128] * bb;
    __syncthreads();
    float acc = lin1_b[j];
    for (int k = 0; k < HIDDEN; ++k) acc += grow[k] * lin1_w[k * 128 + j];
    acc = fmaxf(acc, 0.f);
    float v = acc * lin2_w[j];
#pragma unroll
    for (int ofs = 32; ofs > 0; ofs >>= 1) v += __shfl_down(v, ofs, 64);
    if ((j & 63) == 0) red[j >> 6] = v;
    __syncthreads();
    if (j == 0) out[g] = red[0] + red[1] + lin2_b[0];
}

// ---------------- launch ----------------
extern "C" void kernel_launch(void* const* d_in, const int* in_sizes, int n_in,
                              void* d_out, int out_size, void* d_ws, size_t ws_size,
                              hipStream_t stream) {
    const float* x      = (const float*)d_in[0];
    const int*   ei     = (const int*)d_in[1];
    const int*   batch  = (const int*)d_in[2];
    const float* W1     = (const float*)d_in[3];
    const float* b1     = (const float*)d_in[4];
    const float* W2     = (const float*)d_in[5];
    const float* b2     = (const float*)d_in[6];
    const float* W3     = (const float*)d_in[7];
    const float* b3     = (const float*)d_in[8];
    const float* W4     = (const float*)d_in[9];
    const float* b4     = (const float*)d_in[10];
    const float* lin1_w = (const float*)d_in[11];
    const float* lin1_b = (const float*)d_in[12];
    const float* lin2_w = (const float*)d_in[13];
    const float* lin2_b = (const float*)d_in[14];
    float* out = (float*)d_out;

    char* ws = (char*)d_ws;
    size_t off = 0;
    auto alloc = [&](size_t bytes) -> void* {
        void* p = ws + off;
        off += (bytes + 255) & ~(size_t)255;
        return p;
    };
    __half* tbuf = (__half*)alloc((size_t)N_NODES * HIDDEN * 2);  // 25.6 MB fp16 (GEMM out)
    __half* rbuf = (__half*)alloc((size_t)N_NODES * HIDDEN * 2);  // 25.6 MB fp16 (GEMM in)
    uint2* csr      = (uint2*)alloc((size_t)N_EDGES * 8);
    int*   rowptr   = (int*)alloc((size_t)(N_NODES + 1) * 4);
    int*   deg      = (int*)alloc((size_t)N_NODES * 4);
    int*   cursor   = (int*)alloc((size_t)N_NODES * 4);
    float* dinv     = (float*)alloc((size_t)N_NODES * 4);
    float* ax       = (float*)alloc((size_t)N_NODES * 2 * 4);
    float* gsum     = (float*)alloc((size_t)N_GRAPHS * HIDDEN * 4);
    int*   gbounds  = (int*)alloc((size_t)(N_GRAPHS + 1) * 4);
    int*   bsums    = (int*)alloc((size_t)256 * 4);
    __half* whiT = (__half*)alloc((size_t)3 * 65536 * 2);
    __half* wloT = (__half*)alloc((size_t)3 * 65536 * 2);

    hipMemsetAsync(deg, 0, (size_t)N_NODES * 4, stream);
    hipMemsetAsync(cursor, 0, (size_t)N_NODES * 4, stream);
    hipMemsetAsync(gsum, 0, (size_t)N_GRAPHS * HIDDEN * 4, stream);

    const int TB = 256;
    const int NBLK = (N_NODES + 255) / 256;
    deg_count_kernel<<<(N_EDGES + TB - 1) / TB, TB, 0, stream>>>(ei, deg);
    block_scan_kernel<<<NBLK, 256, 0, stream>>>(deg, rowptr, bsums, dinv);
    scan_bsums_kernel<<<1, 256, 0, stream>>>(bsums, NBLK);
    add_offsets_kernel<<<NBLK, 256, 0, stream>>>(rowptr, bsums);
    fill_csr_kernel<<<(N_EDGES + TB - 1) / TB, TB, 0, stream>>>(ei, rowptr, cursor, dinv, csr);
    wsplit_kernel<<<dim3(256, 3), 256, 0, stream>>>(W2, W3, W4, whiT, wloT);
    bounds_kernel<<<(N_NODES + TB - 1) / TB, TB, 0, stream>>>(batch, gbounds);

    // conv1 stage A: ax = (A x)
    aggx_kernel<<<(N_NODES + TB - 1) / TB, TB, 0, stream>>>(x, rowptr, csr, dinv, ax);

    // conv2..4 (layer-2 GEMM fuses the conv1 expand)
    const int NGB = (N_NODES + 127) / 128;
    const int NAGG = (N_NODES + 3) / 4;
    mfma_gemm_kernel<1><<<NGB, 512, 0, stream>>>(nullptr, ax, W1, b1,
                                                 whiT + 0 * 65536, wloT + 0 * 65536, tbuf);
    agg_full_kernel<<<NAGG, 256, 0, stream>>>(tbuf, rowptr, csr, dinv, b2, rbuf);
    mfma_gemm_kernel<0><<<NGB, 512, 0, stream>>>(rbuf, nullptr, nullptr, nullptr,
                                                 whiT + 1 * 65536, wloT + 1 * 65536, tbuf);
    agg_full_kernel<<<NAGG, 256, 0, stream>>>(tbuf, rowptr, csr, dinv, b3, rbuf);
    mfma_gemm_kernel<0><<<NGB, 512, 0, stream>>>(rbuf, nullptr, nullptr, nullptr,
                                                 whiT + 2 * 65536, wloT + 2 * 65536, tbuf);
    agg_pool2_kernel<<<NAGG, 256, 0, stream>>>(tbuf, rowptr, csr, dinv, batch, gsum);

    // head
    mlp_kernel<<<N_GRAPHS, 128, 0, stream>>>(gsum, gbounds, b4, lin1_w, lin1_b,
                                             lin2_w, lin2_b, out);
}